// Round 1
// baseline (1017.620 us; speedup 1.0000x reference)
//
#include <hip/hip_runtime.h>
#include <math.h>

#define N_NODES 100000
#define N_EDGES 1600000
#define IN_CH   64
#define GCN_CH  64
#define OUT_CH  32

// ---------------------------------------------------------------------------
// 1) degree accumulation: deg[col[e]] += ew[e]
// ---------------------------------------------------------------------------
__global__ void deg_kernel(const int* __restrict__ col, const float* __restrict__ ew,
                           float* __restrict__ deg) {
    int e = blockIdx.x * blockDim.x + threadIdx.x;
    if (e < N_EDGES) atomicAdd(&deg[col[e]], ew[e]);
}

// dis[i] = rsqrt(deg[i] + 1)   (in place)
__global__ void dis_kernel(float* __restrict__ deg_dis) {
    int i = blockIdx.x * blockDim.x + threadIdx.x;
    if (i < N_NODES) deg_dis[i] = rsqrtf(deg_dis[i] + 1.0f);
}

// ---------------------------------------------------------------------------
// 2) dense GEMM  Y[N,64] = X[N,64] @ W[64,64]   (one thread per (row, out_ch))
//    W staged in LDS; 256 threads = 4 rows per block.
// ---------------------------------------------------------------------------
__global__ void gemm64_kernel(const float* __restrict__ X, const float* __restrict__ W,
                              float* __restrict__ Y, int nrows) {
    __shared__ float Ws[64][GCN_CH];
    int t = threadIdx.x;
    for (int i = t; i < 64 * GCN_CH; i += blockDim.x) Ws[i / GCN_CH][i % GCN_CH] = W[i];
    __syncthreads();

    const int rowsPerBlock = 256 / GCN_CH;  // 4
    int lane_c = t & (GCN_CH - 1);
    int sub    = t >> 6;
    int row = blockIdx.x * rowsPerBlock + sub;
    if (row >= nrows) return;
    const float* xr = X + (size_t)row * 64;
    float acc = 0.f;
#pragma unroll
    for (int k = 0; k < 64; ++k) acc = fmaf(xr[k], Ws[k][lane_c], acc);
    Y[(size_t)row * GCN_CH + lane_c] = acc;
}

// ---------------------------------------------------------------------------
// 3) edge scatter: AGG[col[e], ch] += dis[row]·ew·dis[col] · XW[row[e], ch]
//    one thread per (edge, channel); a wave = exactly one edge (64 ch)
// ---------------------------------------------------------------------------
__global__ void scatter_kernel(const int* __restrict__ row, const int* __restrict__ col,
                               const float* __restrict__ ew, const float* __restrict__ dis,
                               const float* __restrict__ XW, float* __restrict__ AGG) {
    long long idx = (long long)blockIdx.x * blockDim.x + threadIdx.x;
    int e  = (int)(idx >> 6);
    int ch = (int)(idx & 63);
    if (e >= N_EDGES) return;
    int r = row[e], c = col[e];
    float norm = dis[r] * ew[e] * dis[c];
    atomicAdd(&AGG[(size_t)c * 64 + ch], norm * XW[(size_t)r * 64 + ch]);
}

// ---------------------------------------------------------------------------
// 4) post: H = relu(AGG + dis^2 * XW + b)
// ---------------------------------------------------------------------------
__global__ void post_kernel(const float* __restrict__ AGG, const float* __restrict__ XW,
                            const float* __restrict__ dis, const float* __restrict__ b,
                            float* __restrict__ H) {
    long long idx = (long long)blockIdx.x * blockDim.x + threadIdx.x;
    if (idx >= (long long)N_NODES * 64) return;
    int node = (int)(idx >> 6);
    int ch   = (int)(idx & 63);
    float d = dis[node];
    float v = AGG[idx] + d * d * XW[idx] + b[ch];
    H[idx] = v > 0.f ? v : 0.f;
}

// ---------------------------------------------------------------------------
// 5) output GEMM + bias + tanh:  Y[N,32] = tanh(H[N,64] @ Wout[64,32] + bout)
// ---------------------------------------------------------------------------
__global__ void out_gemm_kernel(const float* __restrict__ H, const float* __restrict__ W,
                                const float* __restrict__ b, float* __restrict__ Y) {
    __shared__ float Ws[64][OUT_CH];
    int t = threadIdx.x;
    for (int i = t; i < 64 * OUT_CH; i += blockDim.x) Ws[i / OUT_CH][i % OUT_CH] = W[i];
    __syncthreads();

    const int rowsPerBlock = 256 / OUT_CH;  // 8
    int lane_c = t & (OUT_CH - 1);
    int sub    = t >> 5;
    int row = blockIdx.x * rowsPerBlock + sub;
    if (row >= N_NODES) return;
    const float* hr = H + (size_t)row * 64;
    float acc = b[lane_c];
#pragma unroll
    for (int k = 0; k < 64; ++k) acc = fmaf(hr[k], Ws[k][lane_c], acc);
    Y[(size_t)row * OUT_CH + lane_c] = tanhf(acc);
}

// ---------------------------------------------------------------------------
extern "C" void kernel_launch(void* const* d_in, const int* in_sizes, int n_in,
                              void* d_out, int out_size, void* d_ws, size_t ws_size,
                              hipStream_t stream) {
    const float* x     = (const float*)d_in[0];
    const int*   eidx  = (const int*)  d_in[1];
    const float* ew    = (const float*)d_in[2];
    const float* W1    = (const float*)d_in[3];
    const float* b1    = (const float*)d_in[4];
    const float* W2    = (const float*)d_in[5];
    const float* b2    = (const float*)d_in[6];
    const float* Wout  = (const float*)d_in[7];
    const float* bout  = (const float*)d_in[8];
    float*       out   = (float*)d_out;

    const int* row = eidx;             // edge_index[0]
    const int* col = eidx + N_EDGES;   // edge_index[1]

    // workspace layout
    char*  ws   = (char*)d_ws;
    size_t offs = 0;
    auto alloc = [&](size_t bytes) {
        char* p = ws + offs;
        offs += (bytes + 1023) & ~(size_t)1023;
        return p;
    };
    float* dis = (float*)alloc((size_t)N_NODES * sizeof(float));
    float* xw  = (float*)alloc((size_t)N_NODES * GCN_CH * sizeof(float));
    float* agg = (float*)alloc((size_t)N_NODES * GCN_CH * sizeof(float));
    float* h   = (float*)alloc((size_t)N_NODES * GCN_CH * sizeof(float));

    const int BLK = 256;
    const int gEdges   = (N_EDGES + BLK - 1) / BLK;
    const int gNodes   = (N_NODES + BLK - 1) / BLK;
    const int gGemm64  = (N_NODES + 3) / 4;                    // 4 rows/block
    const int gScatter = (int)(((long long)N_EDGES * 64 + BLK - 1) / BLK);
    const int gPost    = (int)(((long long)N_NODES * 64 + BLK - 1) / BLK);
    const int gOut     = (N_NODES + 7) / 8;                    // 8 rows/block

    // degree -> dis
    hipMemsetAsync(dis, 0, (size_t)N_NODES * sizeof(float), stream);
    deg_kernel<<<gEdges, BLK, 0, stream>>>(col, ew, dis);
    dis_kernel<<<gNodes, BLK, 0, stream>>>(dis);

    // ---- layer 1 ----
    gemm64_kernel<<<gGemm64, BLK, 0, stream>>>(x, W1, xw, N_NODES);
    hipMemsetAsync(agg, 0, (size_t)N_NODES * GCN_CH * sizeof(float), stream);
    scatter_kernel<<<gScatter, BLK, 0, stream>>>(row, col, ew, dis, xw, agg);
    post_kernel<<<gPost, BLK, 0, stream>>>(agg, xw, dis, b1, h);

    // ---- layer 2 ----
    gemm64_kernel<<<gGemm64, BLK, 0, stream>>>(h, W2, xw, N_NODES);
    hipMemsetAsync(agg, 0, (size_t)N_NODES * GCN_CH * sizeof(float), stream);
    scatter_kernel<<<gScatter, BLK, 0, stream>>>(row, col, ew, dis, xw, agg);
    post_kernel<<<gPost, BLK, 0, stream>>>(agg, xw, dis, b2, h);

    // ---- output projection ----
    out_gemm_kernel<<<gOut, BLK, 0, stream>>>(h, Wout, bout, out);
}

// Round 2
// 724.675 us; speedup vs baseline: 1.4042x; 1.4042x over previous
//
#include <hip/hip_runtime.h>
#include <math.h>

#define N_NODES 100000
#define N_EDGES 1600000
#define IN_CH   64
#define GCN_CH  64
#define OUT_CH  32

#define SCAN_BLK   256
#define SCAN_ITEMS 4
#define SCAN_CHUNK (SCAN_BLK * SCAN_ITEMS)              // 1024
#define SCAN_NB    ((N_NODES + SCAN_CHUNK - 1) / SCAN_CHUNK)  // 98

// ---------------------------------------------------------------------------
// 1) fused degree (weighted) + in-degree count histogram over col[]
// ---------------------------------------------------------------------------
__global__ void deg_count_kernel(const int* __restrict__ col, const float* __restrict__ ew,
                                 float* __restrict__ deg_w, int* __restrict__ cnt) {
    int e = blockIdx.x * blockDim.x + threadIdx.x;
    if (e >= N_EDGES) return;
    int c = col[e];
    atomicAdd(&deg_w[c], ew[e]);
    atomicAdd(&cnt[c], 1);
}

// dis[i] = rsqrt(deg_w[i] + 1)   (in place)
__global__ void dis_kernel(float* __restrict__ deg_dis) {
    int i = blockIdx.x * blockDim.x + threadIdx.x;
    if (i < N_NODES) deg_dis[i] = rsqrtf(deg_dis[i] + 1.0f);
}

// ---------------------------------------------------------------------------
// 2) 3-kernel exclusive scan of cnt[N_NODES] -> rowptr[N_NODES+1]
// ---------------------------------------------------------------------------
__global__ void scan1_kernel(const int* __restrict__ cnt, int* __restrict__ rowptr,
                             int* __restrict__ blockSums) {
    __shared__ int sdata[SCAN_BLK];
    int t = threadIdx.x;
    int base = blockIdx.x * SCAN_CHUNK + t * SCAN_ITEMS;
    int v[SCAN_ITEMS];
    int sum = 0;
#pragma unroll
    for (int i = 0; i < SCAN_ITEMS; ++i) {
        int idx = base + i;
        v[i] = (idx < N_NODES) ? cnt[idx] : 0;
        sum += v[i];
    }
    sdata[t] = sum;
    __syncthreads();
    // Hillis-Steele inclusive scan over thread sums
    for (int off = 1; off < SCAN_BLK; off <<= 1) {
        int x = (t >= off) ? sdata[t - off] : 0;
        __syncthreads();
        sdata[t] += x;
        __syncthreads();
    }
    int excl = sdata[t] - sum;  // exclusive prefix of this thread within block
    if (t == SCAN_BLK - 1) blockSums[blockIdx.x] = sdata[t];
    int run = excl;
#pragma unroll
    for (int i = 0; i < SCAN_ITEMS; ++i) {
        int idx = base + i;
        if (idx < N_NODES) rowptr[idx] = run;
        run += v[i];
    }
}

__global__ void scan2_kernel(int* __restrict__ blockSums) {
    __shared__ int s[128];
    int t = threadIdx.x;
    int orig = (t < SCAN_NB) ? blockSums[t] : 0;
    s[t] = orig;
    __syncthreads();
    for (int off = 1; off < 128; off <<= 1) {
        int x = (t >= off) ? s[t - off] : 0;
        __syncthreads();
        s[t] += x;
        __syncthreads();
    }
    if (t < SCAN_NB) blockSums[t] = s[t] - orig;  // exclusive
}

__global__ void scan3_kernel(int* __restrict__ rowptr, const int* __restrict__ blockSums) {
    int i = blockIdx.x * blockDim.x + threadIdx.x;
    if (i < N_NODES) rowptr[i] += blockSums[i / SCAN_CHUNK];
    if (i == 0) rowptr[N_NODES] = N_EDGES;
}

// ---------------------------------------------------------------------------
// 3) bucket fill: permute (row, norm) into CSR-by-col order.
//    cnt[] is consumed (atomicSub) — it held the original histogram.
// ---------------------------------------------------------------------------
__global__ void fill_kernel(const int* __restrict__ row, const int* __restrict__ col,
                            const float* __restrict__ ew, const float* __restrict__ dis,
                            const int* __restrict__ rowptr, int* __restrict__ cnt,
                            int* __restrict__ srcIdx, float* __restrict__ normv) {
    int e = blockIdx.x * blockDim.x + threadIdx.x;
    if (e >= N_EDGES) return;
    int r = row[e], c = col[e];
    int k = atomicSub(&cnt[c], 1) - 1;    // 0..deg-1 (reversed; order irrelevant)
    int slot = rowptr[c] + k;
    srcIdx[slot] = r;
    normv[slot]  = dis[r] * ew[e] * dis[c];
}

// ---------------------------------------------------------------------------
// 4) dense GEMM  Y[N,64] = X[N,64] @ W[64,64]
// ---------------------------------------------------------------------------
__global__ void gemm64_kernel(const float* __restrict__ X, const float* __restrict__ W,
                              float* __restrict__ Y, int nrows) {
    __shared__ float Ws[64][GCN_CH];
    int t = threadIdx.x;
    for (int i = t; i < 64 * GCN_CH; i += blockDim.x) Ws[i / GCN_CH][i % GCN_CH] = W[i];
    __syncthreads();

    int lane_c = t & (GCN_CH - 1);
    int sub    = t >> 6;
    int row = blockIdx.x * 4 + sub;
    if (row >= nrows) return;
    const float* xr = X + (size_t)row * 64;
    float acc = 0.f;
#pragma unroll
    for (int k = 0; k < 64; ++k) acc = fmaf(xr[k], Ws[k][lane_c], acc);
    Y[(size_t)row * GCN_CH + lane_c] = acc;
}

// ---------------------------------------------------------------------------
// 5) fused gather + self-loop + bias + relu:
//    H[n,ch] = relu( sum_{s in in(n)} norm[s]*XW[src[s],ch] + dis[n]^2*XW[n,ch] + b[ch] )
//    one wave per node, lane = channel
// ---------------------------------------------------------------------------
__global__ void gather_fused_kernel(const int* __restrict__ rowptr, const int* __restrict__ srcIdx,
                                    const float* __restrict__ normv, const float* __restrict__ XW,
                                    const float* __restrict__ dis, const float* __restrict__ b,
                                    float* __restrict__ H) {
    int node = blockIdx.x * (blockDim.x >> 6) + (threadIdx.x >> 6);
    int ch   = threadIdx.x & 63;
    if (node >= N_NODES) return;
    int beg = rowptr[node], end = rowptr[node + 1];
    float acc = 0.f;
    for (int s = beg; s < end; ++s) {
        int   src = srcIdx[s];   // wave-uniform: L1 broadcast
        float nv  = normv[s];
        acc = fmaf(nv, XW[(size_t)src * 64 + ch], acc);
    }
    float d = dis[node];
    float v = fmaf(d * d, XW[(size_t)node * 64 + ch], acc) + b[ch];
    H[(size_t)node * 64 + ch] = fmaxf(v, 0.f);
}

// ---------------------------------------------------------------------------
// 6) output GEMM + bias + tanh:  Y[N,32] = tanh(H[N,64] @ Wout[64,32] + bout)
// ---------------------------------------------------------------------------
__global__ void out_gemm_kernel(const float* __restrict__ H, const float* __restrict__ W,
                                const float* __restrict__ b, float* __restrict__ Y) {
    __shared__ float Ws[64][OUT_CH];
    int t = threadIdx.x;
    for (int i = t; i < 64 * OUT_CH; i += blockDim.x) Ws[i / OUT_CH][i % OUT_CH] = W[i];
    __syncthreads();

    int lane_c = t & (OUT_CH - 1);
    int sub    = t >> 5;
    int row = blockIdx.x * 8 + sub;
    if (row >= N_NODES) return;
    const float* hr = H + (size_t)row * 64;
    float acc = b[lane_c];
#pragma unroll
    for (int k = 0; k < 64; ++k) acc = fmaf(hr[k], Ws[k][lane_c], acc);
    Y[(size_t)row * OUT_CH + lane_c] = tanhf(acc);
}

// ---------------------------------------------------------------------------
extern "C" void kernel_launch(void* const* d_in, const int* in_sizes, int n_in,
                              void* d_out, int out_size, void* d_ws, size_t ws_size,
                              hipStream_t stream) {
    const float* x     = (const float*)d_in[0];
    const int*   eidx  = (const int*)  d_in[1];
    const float* ew    = (const float*)d_in[2];
    const float* W1    = (const float*)d_in[3];
    const float* b1    = (const float*)d_in[4];
    const float* W2    = (const float*)d_in[5];
    const float* b2    = (const float*)d_in[6];
    const float* Wout  = (const float*)d_in[7];
    const float* bout  = (const float*)d_in[8];
    float*       out   = (float*)d_out;

    const int* row = eidx;             // edge_index[0]
    const int* col = eidx + N_EDGES;   // edge_index[1]

    // workspace layout
    char*  ws   = (char*)d_ws;
    size_t offs = 0;
    auto alloc = [&](size_t bytes) {
        char* p = ws + offs;
        offs += (bytes + 1023) & ~(size_t)1023;
        return p;
    };
    float* dis       = (float*)alloc((size_t)N_NODES * sizeof(float));   // deg_w -> dis
    int*   cnt       = (int*)  alloc((size_t)N_NODES * sizeof(int));
    int*   rowptr    = (int*)  alloc((size_t)(N_NODES + 1) * sizeof(int));
    int*   blockSums = (int*)  alloc((size_t)SCAN_NB * sizeof(int));
    int*   srcIdx    = (int*)  alloc((size_t)N_EDGES * sizeof(int));
    float* normv     = (float*)alloc((size_t)N_EDGES * sizeof(float));
    float* xw        = (float*)alloc((size_t)N_NODES * GCN_CH * sizeof(float));
    float* h         = (float*)alloc((size_t)N_NODES * GCN_CH * sizeof(float));

    const int BLK = 256;
    const int gEdges  = (N_EDGES + BLK - 1) / BLK;
    const int gNodes  = (N_NODES + BLK - 1) / BLK;
    const int gGemm64 = (N_NODES + 3) / 4;   // 4 rows/block
    const int gGather = (N_NODES + 3) / 4;   // 4 nodes/block (1 wave each)
    const int gOut    = (N_NODES + 7) / 8;   // 8 rows/block

    // ---- graph preprocessing (once per call, shared by both layers) ----
    hipMemsetAsync(dis, 0, (size_t)N_NODES * sizeof(float), stream);
    hipMemsetAsync(cnt, 0, (size_t)N_NODES * sizeof(int), stream);
    deg_count_kernel<<<gEdges, BLK, 0, stream>>>(col, ew, dis, cnt);
    dis_kernel<<<gNodes, BLK, 0, stream>>>(dis);
    scan1_kernel<<<SCAN_NB, SCAN_BLK, 0, stream>>>(cnt, rowptr, blockSums);
    scan2_kernel<<<1, 128, 0, stream>>>(blockSums);
    scan3_kernel<<<gNodes, BLK, 0, stream>>>(rowptr, blockSums);
    fill_kernel<<<gEdges, BLK, 0, stream>>>(row, col, ew, dis, rowptr, cnt, srcIdx, normv);

    // ---- layer 1 ----
    gemm64_kernel<<<gGemm64, BLK, 0, stream>>>(x, W1, xw, N_NODES);
    gather_fused_kernel<<<gGather, BLK, 0, stream>>>(rowptr, srcIdx, normv, xw, dis, b1, h);

    // ---- layer 2 ----
    gemm64_kernel<<<gGemm64, BLK, 0, stream>>>(h, W2, xw, N_NODES);
    gather_fused_kernel<<<gGather, BLK, 0, stream>>>(rowptr, srcIdx, normv, xw, dis, b2, h);

    // ---- output projection ----
    out_gemm_kernel<<<gOut, BLK, 0, stream>>>(h, Wout, bout, out);
}